// Round 1
// baseline (838.326 us; speedup 1.0000x reference)
//
#include <hip/hip_runtime.h>
#include <stdint.h>

#define D 512

typedef __bf16 bf16x8 __attribute__((ext_vector_type(8)));
typedef float f32x4 __attribute__((ext_vector_type(4)));

static __device__ __forceinline__ unsigned short f2bf(float f) {
  unsigned int u = __builtin_bit_cast(unsigned int, f);
  u += 0x7fffu + ((u >> 16) & 1u);
  return (unsigned short)(u >> 16);
}
static __device__ __forceinline__ unsigned int pack2(float lo, float hi) {
  return (unsigned int)f2bf(lo) | ((unsigned int)f2bf(hi) << 16);
}
static __device__ __forceinline__ float bflo(unsigned int u) {
  return __builtin_bit_cast(float, u << 16);
}
static __device__ __forceinline__ float bfhi(unsigned int u) {
  return __builtin_bit_cast(float, u & 0xffff0000u);
}

// ---------------- prep: Wcat (bf16, [h][k|v][d][i]) + bcat + WqT ----------------
__global__ __launch_bounds__(256) void prep_k(
    const float* __restrict__ Wq, const float* __restrict__ Wk,
    const float* __restrict__ bk, const float* __restrict__ Wv,
    const float* __restrict__ bv, unsigned short* __restrict__ Wcat,
    float* __restrict__ bcat, float* __restrict__ WqT) {
  int bid = blockIdx.x, tid = threadIdx.x;
  if (bid < 1024) {
    int h = bid >> 7, kvs = (bid >> 6) & 1, d = bid & 63;
    int srow = h * 64 + d;
    const float* src = (kvs ? Wv : Wk) + (size_t)srow * D;
    unsigned short* dst = Wcat + (size_t)bid * D;
    for (int i = tid; i < D; i += 256) dst[i] = f2bf(src[i]);
    if (tid == 0) bcat[bid] = (kvs ? bv : bk)[srow];
  } else {
    int i = bid - 1024;
    for (int o = tid; o < D; o += 256) WqT[(size_t)i * D + o] = Wq[(size_t)o * D + i];
  }
}

// ---------------- qproj: q16[16][77][512] = LN(xf) @ Wq^T + bq (f32) ----------------
__global__ __launch_bounds__(256) void qproj_k(
    const float* __restrict__ xf, const float* __restrict__ tn_g,
    const float* __restrict__ tn_b, const float* __restrict__ WqT,
    const float* __restrict__ bq, float* __restrict__ q16) {
  __shared__ __align__(16) float xnq[11][512];
  int bs = blockIdx.x, n0 = blockIdx.y * 11;
  int tid = threadIdx.x, wv = tid >> 6, lane = tid & 63;

  for (int lr = wv; lr < 11; lr += 4) {
    const f32x4* xr = (const f32x4*)(xf + ((size_t)(bs * 77 + n0 + lr)) * D);
    f32x4 va = xr[lane * 2], vb = xr[lane * 2 + 1];
    float s = va[0] + va[1] + va[2] + va[3] + vb[0] + vb[1] + vb[2] + vb[3];
    float sq = va[0] * va[0] + va[1] * va[1] + va[2] * va[2] + va[3] * va[3] +
               vb[0] * vb[0] + vb[1] * vb[1] + vb[2] * vb[2] + vb[3] * vb[3];
#pragma unroll
    for (int off = 32; off; off >>= 1) {
      s += __shfl_xor(s, off);
      sq += __shfl_xor(sq, off);
    }
    float mu = s * (1.0f / 512.0f);
    float var = sq * (1.0f / 512.0f) - mu * mu;
    float rstd = rsqrtf(var + 1e-5f);
    f32x4 ga = ((const f32x4*)tn_g)[lane * 2], gb = ((const f32x4*)tn_g)[lane * 2 + 1];
    f32x4 ba = ((const f32x4*)tn_b)[lane * 2], bb = ((const f32x4*)tn_b)[lane * 2 + 1];
    f32x4 r0, r1;
#pragma unroll
    for (int j = 0; j < 4; ++j) {
      r0[j] = (va[j] - mu) * rstd * ga[j] + ba[j];
      r1[j] = (vb[j] - mu) * rstd * gb[j] + bb[j];
    }
    *(f32x4*)&xnq[lr][lane * 8] = r0;
    *(f32x4*)&xnq[lr][lane * 8 + 4] = r1;
  }
  __syncthreads();

  int rows[3];
  int nr = 0;
  for (int lr = wv; lr < 11; lr += 4) rows[nr++] = lr;
  f32x4 acc[3][2];
  f32x4 bq0 = ((const f32x4*)bq)[lane], bq1 = ((const f32x4*)bq)[64 + lane];
#pragma unroll
  for (int r = 0; r < 3; ++r) {
    acc[r][0] = bq0;
    acc[r][1] = bq1;
  }
  for (int i = 0; i < 512; ++i) {
    const f32x4* wr = (const f32x4*)(WqT + (size_t)i * D);
    f32x4 w0 = wr[lane], w1 = wr[64 + lane];
#pragma unroll
    for (int r = 0; r < 3; ++r) {
      if (r < nr) {
        float xv = xnq[rows[r]][i];
        acc[r][0] += xv * w0;
        acc[r][1] += xv * w1;
      }
    }
  }
  for (int r = 0; r < nr; ++r) {
    float* dst = q16 + ((size_t)(bs * 77 + n0 + rows[r])) * D;
    *(f32x4*)(dst + lane * 4) = acc[r][0];
    *(f32x4*)(dst + 256 + lane * 4) = acc[r][1];
  }
}

// ---------------- fused: LN(x) -> k,v proj (MFMA bf16) -> attention -> out ----------------
// block: 2 batches (34 rows), 256 threads (4 waves), loop over 4 head-pairs.
// LDS: xn bf16 [34][520] (pad: 1040B row stride, 16B-aligned, bank-stride 4)
//      kv bf16 [34][264]  (cols: hh*128 + (k?0:64) + d)
__global__ __launch_bounds__(256) void fused_k(
    const float* __restrict__ x, const float* __restrict__ n_g,
    const float* __restrict__ n_b, const unsigned short* __restrict__ Wcat,
    const float* __restrict__ bcat, const float* __restrict__ q16,
    float* __restrict__ out) {
  __shared__ __align__(16) unsigned short xn_s[34 * 520];
  __shared__ __align__(16) unsigned short kv_s[34 * 264];
  const int b0 = blockIdx.x * 2;
  const int tid = threadIdx.x, wv = tid >> 6, lane = tid & 63;
  const int l15 = lane & 15, lhi = lane >> 4;

  // Phase 1: LayerNorm -> xn bf16 in LDS
  for (int rr = wv; rr < 34; rr += 4) {
    const f32x4* xr = (const f32x4*)(x + ((size_t)(b0 * 17 + rr)) * D);
    f32x4 va = xr[lane * 2], vb = xr[lane * 2 + 1];
    float s = va[0] + va[1] + va[2] + va[3] + vb[0] + vb[1] + vb[2] + vb[3];
    float sq = va[0] * va[0] + va[1] * va[1] + va[2] * va[2] + va[3] * va[3] +
               vb[0] * vb[0] + vb[1] * vb[1] + vb[2] * vb[2] + vb[3] * vb[3];
#pragma unroll
    for (int off = 32; off; off >>= 1) {
      s += __shfl_xor(s, off);
      sq += __shfl_xor(sq, off);
    }
    float mu = s * (1.0f / 512.0f);
    float var = sq * (1.0f / 512.0f) - mu * mu;
    float rstd = rsqrtf(var + 1e-5f);
    f32x4 ga = ((const f32x4*)n_g)[lane * 2], gb = ((const f32x4*)n_g)[lane * 2 + 1];
    f32x4 ba = ((const f32x4*)n_b)[lane * 2], bb = ((const f32x4*)n_b)[lane * 2 + 1];
    float f0 = (va[0] - mu) * rstd * ga[0] + ba[0];
    float f1 = (va[1] - mu) * rstd * ga[1] + ba[1];
    float f2 = (va[2] - mu) * rstd * ga[2] + ba[2];
    float f3 = (va[3] - mu) * rstd * ga[3] + ba[3];
    float f4 = (vb[0] - mu) * rstd * gb[0] + bb[0];
    float f5 = (vb[1] - mu) * rstd * gb[1] + bb[1];
    float f6 = (vb[2] - mu) * rstd * gb[2] + bb[2];
    float f7 = (vb[3] - mu) * rstd * gb[3] + bb[3];
    uint4 u;
    u.x = pack2(f0, f1);
    u.y = pack2(f2, f3);
    u.z = pack2(f4, f5);
    u.w = pack2(f6, f7);
    *reinterpret_cast<uint4*>(xn_s + rr * 520 + lane * 8) = u;
  }
  __syncthreads();

  for (int hp = 0; hp < 4; ++hp) {
    // ---- k,v projection via MFMA: cols = Wcat rows [hp*256, hp*256+256) ----
    const int ntb = wv * 4;  // this wave's first n-tile (16 tiles over 4 waves)
    f32x4 acc[3][4];
#pragma unroll
    for (int nt = 0; nt < 4; ++nt) {
      float bias = bcat[hp * 256 + (ntb + nt) * 16 + l15];
      f32x4 bi = {bias, bias, bias, bias};
#pragma unroll
      for (int mt = 0; mt < 3; ++mt) acc[mt][nt] = bi;
    }
    const unsigned short* wbase = Wcat + (size_t)(hp * 256 + ntb * 16 + l15) * D;
    for (int ks = 0; ks < 16; ++ks) {
      bf16x8 bf[4];
#pragma unroll
      for (int nt = 0; nt < 4; ++nt)
        bf[nt] = *(const bf16x8*)(wbase + (size_t)nt * 16 * D + ks * 32 + lhi * 8);
#pragma unroll
      for (int mt = 0; mt < 3; ++mt) {
        bf16x8 af = *(const bf16x8*)(xn_s + (mt * 16 + l15) * 520 + ks * 32 + lhi * 8);
#pragma unroll
        for (int nt = 0; nt < 4; ++nt)
          acc[mt][nt] =
              __builtin_amdgcn_mfma_f32_16x16x32_bf16(af, bf[nt], acc[mt][nt], 0, 0, 0);
      }
    }
    // store kv tile to LDS (C layout: col=lane&15, row=(lane>>4)*4+r)
#pragma unroll
    for (int mt = 0; mt < 3; ++mt)
#pragma unroll
      for (int nt = 0; nt < 4; ++nt) {
        int c = (ntb + nt) * 16 + l15;
#pragma unroll
        for (int r = 0; r < 4; ++r) {
          int row = mt * 16 + lhi * 4 + r;
          if (row < 34) kv_s[row * 264 + c] = f2bf(acc[mt][nt][r]);
        }
      }
    __syncthreads();

    // ---- attention for heads hp*2, hp*2+1 ----
    for (int base = 0; base < 308; base += 256) {
      int item = base + tid;
      if (item < 308) {
        int hh = item / 154, rem = item % 154;
        int bb = rem / 77, n = rem % 77;
        int b = b0 + bb;
        const f32x4* qr =
            (const f32x4*)(q16 + ((size_t)((b & 15) * 77 + n)) * D + (hp * 2 + hh) * 64);
        f32x4 q[16];
#pragma unroll
        for (int i = 0; i < 16; ++i) q[i] = qr[i];
        float lg[17];
        const unsigned short* kbase = kv_s + hh * 128;
#pragma unroll
        for (int m = 0; m < 17; ++m) {
          const uint4* kr = (const uint4*)(kbase + (bb * 17 + m) * 264);
          float a = 0.f;
#pragma unroll
          for (int dc = 0; dc < 8; ++dc) {
            uint4 kk = kr[dc];
            f32x4 qa = q[dc * 2], qb = q[dc * 2 + 1];
            a += bflo(kk.x) * qa[0] + bfhi(kk.x) * qa[1] + bflo(kk.y) * qa[2] +
                 bfhi(kk.y) * qa[3] + bflo(kk.z) * qb[0] + bfhi(kk.z) * qb[1] +
                 bflo(kk.w) * qb[2] + bfhi(kk.w) * qb[3];
          }
          lg[m] = a * 0.125f;
        }
        float mx = lg[0];
#pragma unroll
        for (int m = 1; m < 17; ++m) mx = fmaxf(mx, lg[m]);
        float ssum = 0.f;
#pragma unroll
        for (int m = 0; m < 17; ++m) {
          float e = __expf(lg[m] - mx);
          lg[m] = e;
          ssum += e;
        }
        float inv = 1.0f / ssum;
        float* dst = out + ((size_t)b * 77 + n) * D + (hp * 2 + hh) * 64;
        const unsigned short* vbase = kv_s + hh * 128 + 64;
#pragma unroll
        for (int dc = 0; dc < 8; ++dc) {
          f32x4 o0 = {0.f, 0.f, 0.f, 0.f}, o1 = {0.f, 0.f, 0.f, 0.f};
#pragma unroll
          for (int m = 0; m < 17; ++m) {
            const uint4* vr = (const uint4*)(vbase + (bb * 17 + m) * 264);
            uint4 vvv = vr[dc];
            float wm = lg[m];
            o0[0] += wm * bflo(vvv.x);
            o0[1] += wm * bfhi(vvv.x);
            o0[2] += wm * bflo(vvv.y);
            o0[3] += wm * bfhi(vvv.y);
            o1[0] += wm * bflo(vvv.z);
            o1[1] += wm * bfhi(vvv.z);
            o1[2] += wm * bflo(vvv.w);
            o1[3] += wm * bfhi(vvv.w);
          }
          *(f32x4*)(dst + dc * 8) = o0 * inv;
          *(f32x4*)(dst + dc * 8 + 4) = o1 * inv;
        }
      }
    }
    __syncthreads();
  }
}

extern "C" void kernel_launch(void* const* d_in, const int* in_sizes, int n_in,
                              void* d_out, int out_size, void* d_ws, size_t ws_size,
                              hipStream_t stream) {
  const float* xf = (const float*)d_in[0];
  const float* x = (const float*)d_in[1];
  const float* tn_g = (const float*)d_in[2];
  const float* tn_b = (const float*)d_in[3];
  const float* n_g = (const float*)d_in[4];
  const float* n_b = (const float*)d_in[5];
  const float* Wq = (const float*)d_in[6];
  const float* bq = (const float*)d_in[7];
  const float* Wk = (const float*)d_in[8];
  const float* bk = (const float*)d_in[9];
  const float* Wv = (const float*)d_in[10];
  const float* bv = (const float*)d_in[11];
  float* out = (float*)d_out;

  char* ws = (char*)d_ws;
  float* q16 = (float*)ws;                                   // 16*77*512*4 = 2,523,136 B
  unsigned short* Wcat = (unsigned short*)(ws + 2523136);    // 1024*512*2  = 1,048,576 B
  float* bcat = (float*)(ws + 3571712);                      // 1024*4      = 4,096 B
  float* WqT = (float*)(ws + 3575808);                       // 512*512*4   = 1,048,576 B

  prep_k<<<1536, 256, 0, stream>>>(Wq, Wk, bk, Wv, bv, Wcat, bcat, WqT);
  qproj_k<<<dim3(16, 7), 256, 0, stream>>>(xf, tn_g, tn_b, WqT, bq, q16);
  fused_k<<<1944, 256, 0, stream>>>(x, n_g, n_b, Wcat, bcat, q16, out);
}

// Round 3
// 639.513 us; speedup vs baseline: 1.3109x; 1.3109x over previous
//
#include <hip/hip_runtime.h>
#include <stdint.h>

#define D 512

typedef _Float16 f16;
typedef f16 f16x8 __attribute__((ext_vector_type(8)));
typedef f16 h2 __attribute__((ext_vector_type(2)));
typedef float f32x4 __attribute__((ext_vector_type(4)));

static __device__ __forceinline__ h2 bch(unsigned int u) {
  return __builtin_bit_cast(h2, u);
}
static __device__ __forceinline__ unsigned int bcu(h2 h) {
  return __builtin_bit_cast(unsigned int, h);
}
static __device__ __forceinline__ h2 pkrtz(float a, float b) {
  return __builtin_bit_cast(h2, __builtin_amdgcn_cvt_pkrtz(a, b));
}

#if __has_builtin(__builtin_amdgcn_fdot2)
#define FDOT2(a, b, c) __builtin_amdgcn_fdot2((a), (b), (c), false)
#else
static __device__ __forceinline__ float FDOT2(h2 a, h2 b, float c) {
  return (float)a[0] * (float)b[0] + ((float)a[1] * (float)b[1] + c);
}
#endif

// ---------------- prep: Wcat (f16, [h][k|v][d][i]) + bcat + WqT ----------------
__global__ __launch_bounds__(256) void prep_k(
    const float* __restrict__ Wq, const float* __restrict__ Wk,
    const float* __restrict__ bk, const float* __restrict__ Wv,
    const float* __restrict__ bv, f16* __restrict__ Wcat,
    float* __restrict__ bcat, float* __restrict__ WqT) {
  int bid = blockIdx.x, tid = threadIdx.x;
  if (bid < 1024) {
    int h = bid >> 7, kvs = (bid >> 6) & 1, d = bid & 63;
    int srow = h * 64 + d;
    const float* src = (kvs ? Wv : Wk) + (size_t)srow * D;
    f16* dst = Wcat + (size_t)bid * D;
    for (int i = tid; i < D; i += 256) dst[i] = (f16)src[i];
    if (tid == 0) bcat[bid] = (kvs ? bv : bk)[srow];
  } else {
    int i = bid - 1024;
    for (int o = tid; o < D; o += 256) WqT[(size_t)i * D + o] = Wq[(size_t)o * D + i];
  }
}

// ---------------- qproj: q16h[h][bs][n][64] (f16) = LN(xf) @ Wq^T + bq ----------------
__global__ __launch_bounds__(256) void qproj_k(
    const float* __restrict__ xf, const float* __restrict__ tn_g,
    const float* __restrict__ tn_b, const float* __restrict__ WqT,
    const float* __restrict__ bq, f16* __restrict__ q16h) {
  __shared__ __align__(16) float xnq[11][512];
  int bs = blockIdx.x, n0 = blockIdx.y * 11;
  int tid = threadIdx.x, wv = tid >> 6, lane = tid & 63;

  for (int lr = wv; lr < 11; lr += 4) {
    const f32x4* xr = (const f32x4*)(xf + ((size_t)(bs * 77 + n0 + lr)) * D);
    f32x4 va = xr[lane * 2], vb = xr[lane * 2 + 1];
    float s = va[0] + va[1] + va[2] + va[3] + vb[0] + vb[1] + vb[2] + vb[3];
    float sq = va[0] * va[0] + va[1] * va[1] + va[2] * va[2] + va[3] * va[3] +
               vb[0] * vb[0] + vb[1] * vb[1] + vb[2] * vb[2] + vb[3] * vb[3];
#pragma unroll
    for (int off = 32; off; off >>= 1) {
      s += __shfl_xor(s, off);
      sq += __shfl_xor(sq, off);
    }
    float mu = s * (1.0f / 512.0f);
    float var = sq * (1.0f / 512.0f) - mu * mu;
    float rstd = rsqrtf(var + 1e-5f);
    f32x4 ga = ((const f32x4*)tn_g)[lane * 2], gb = ((const f32x4*)tn_g)[lane * 2 + 1];
    f32x4 ba = ((const f32x4*)tn_b)[lane * 2], bb = ((const f32x4*)tn_b)[lane * 2 + 1];
    f32x4 r0, r1;
#pragma unroll
    for (int j = 0; j < 4; ++j) {
      r0[j] = (va[j] - mu) * rstd * ga[j] + ba[j];
      r1[j] = (vb[j] - mu) * rstd * gb[j] + bb[j];
    }
    *(f32x4*)&xnq[lr][lane * 8] = r0;
    *(f32x4*)&xnq[lr][lane * 8 + 4] = r1;
  }
  __syncthreads();

  int rows[3];
  int nr = 0;
  for (int lr = wv; lr < 11; lr += 4) rows[nr++] = lr;
  f32x4 acc[3][2];
  f32x4 bq0 = ((const f32x4*)bq)[lane], bq1 = ((const f32x4*)bq)[64 + lane];
#pragma unroll
  for (int r = 0; r < 3; ++r) {
    acc[r][0] = bq0;
    acc[r][1] = bq1;
  }
  for (int i = 0; i < 512; ++i) {
    const f32x4* wr = (const f32x4*)(WqT + (size_t)i * D);
    f32x4 w0 = wr[lane], w1 = wr[64 + lane];
#pragma unroll
    for (int r = 0; r < 3; ++r) {
      if (r < nr) {
        float xv = xnq[rows[r]][i];
        acc[r][0] += xv * w0;
        acc[r][1] += xv * w1;
      }
    }
  }
  int h0 = lane >> 4, d0 = (lane * 4) & 63;
  for (int r = 0; r < nr; ++r) {
    int n = n0 + rows[r];
    uint2 p0, p1;
    p0.x = bcu(pkrtz(acc[r][0][0], acc[r][0][1]));
    p0.y = bcu(pkrtz(acc[r][0][2], acc[r][0][3]));
    p1.x = bcu(pkrtz(acc[r][1][0], acc[r][1][1]));
    p1.y = bcu(pkrtz(acc[r][1][2], acc[r][1][3]));
    *(uint2*)(q16h + (((size_t)h0 * 16 + bs) * 77 + n) * 64 + d0) = p0;
    *(uint2*)(q16h + (((size_t)(h0 + 4) * 16 + bs) * 77 + n) * 64 + d0) = p1;
  }
}

// ---------------- fused: LN(x) -> k,v proj (MFMA f16) -> attention (dot2/pk_fma) ----------------
// block: 2 batches (34 rows), 256 threads (4 waves), loop over 4 head-pairs.
// LDS: xn f16 [34][520] (1040B row stride, 16B-aligned, bank-stride 4 -> ~2-way)
//      K_s/V_s f16 [2 hh][2 bb][17][64] (reads are broadcast -> conflict-free)
__global__ __launch_bounds__(256, 3) void fused_k(
    const float* __restrict__ x, const float* __restrict__ n_g,
    const float* __restrict__ n_b, const f16* __restrict__ Wcat,
    const float* __restrict__ bcat, const f16* __restrict__ q16h,
    float* __restrict__ out) {
  __shared__ __align__(16) f16 xn_s[34 * 520];
  __shared__ __align__(16) f16 K_s[2 * 2 * 17 * 64];
  __shared__ __align__(16) f16 V_s[2 * 2 * 17 * 64];
  const int b0 = blockIdx.x * 2;
  const int tid = threadIdx.x, wv = tid >> 6, lane = tid & 63;
  const int l15 = lane & 15, lhi = lane >> 4;

  // Phase 1: LayerNorm -> xn f16 in LDS
  for (int rr = wv; rr < 34; rr += 4) {
    const f32x4* xr = (const f32x4*)(x + ((size_t)(b0 * 17 + rr)) * D);
    f32x4 va = xr[lane * 2], vb = xr[lane * 2 + 1];
    float s = va[0] + va[1] + va[2] + va[3] + vb[0] + vb[1] + vb[2] + vb[3];
    float sq = va[0] * va[0] + va[1] * va[1] + va[2] * va[2] + va[3] * va[3] +
               vb[0] * vb[0] + vb[1] * vb[1] + vb[2] * vb[2] + vb[3] * vb[3];
#pragma unroll
    for (int off = 32; off; off >>= 1) {
      s += __shfl_xor(s, off);
      sq += __shfl_xor(sq, off);
    }
    float mu = s * (1.0f / 512.0f);
    float var = sq * (1.0f / 512.0f) - mu * mu;
    float rstd = rsqrtf(var + 1e-5f);
    f32x4 ga = ((const f32x4*)n_g)[lane * 2], gb = ((const f32x4*)n_g)[lane * 2 + 1];
    f32x4 ba = ((const f32x4*)n_b)[lane * 2], bb = ((const f32x4*)n_b)[lane * 2 + 1];
    float f0 = (va[0] - mu) * rstd * ga[0] + ba[0];
    float f1 = (va[1] - mu) * rstd * ga[1] + ba[1];
    float f2 = (va[2] - mu) * rstd * ga[2] + ba[2];
    float f3 = (va[3] - mu) * rstd * ga[3] + ba[3];
    float f4 = (vb[0] - mu) * rstd * gb[0] + bb[0];
    float f5 = (vb[1] - mu) * rstd * gb[1] + bb[1];
    float f6 = (vb[2] - mu) * rstd * gb[2] + bb[2];
    float f7 = (vb[3] - mu) * rstd * gb[3] + bb[3];
    uint4 u;
    u.x = bcu(pkrtz(f0, f1));
    u.y = bcu(pkrtz(f2, f3));
    u.z = bcu(pkrtz(f4, f5));
    u.w = bcu(pkrtz(f6, f7));
    *reinterpret_cast<uint4*>(xn_s + rr * 520 + lane * 8) = u;
  }
  __syncthreads();

  for (int hp = 0; hp < 4; ++hp) {
    // ---- k,v projection via MFMA f16: cols = Wcat rows [hp*256, hp*256+256) ----
    const int ntb = wv * 4;  // wave's 4 n-tiles cover cols [wv*64, wv*64+64)
    f32x4 acc[3][4];
#pragma unroll
    for (int nt = 0; nt < 4; ++nt) {
      float bias = bcat[hp * 256 + (ntb + nt) * 16 + l15];
      f32x4 bi = {bias, bias, bias, bias};
#pragma unroll
      for (int mt = 0; mt < 3; ++mt) acc[mt][nt] = bi;
    }
    const f16* wbase = Wcat + (size_t)(hp * 256 + ntb * 16 + l15) * D;
    for (int ks = 0; ks < 16; ++ks) {
      f16x8 bf[4];
#pragma unroll
      for (int nt = 0; nt < 4; ++nt)
        bf[nt] = *(const f16x8*)(wbase + (size_t)nt * 16 * D + ks * 32 + lhi * 8);
#pragma unroll
      for (int mt = 0; mt < 3; ++mt) {
        f16x8 af = *(const f16x8*)(xn_s + (mt * 16 + l15) * 520 + ks * 32 + lhi * 8);
#pragma unroll
        for (int nt = 0; nt < 4; ++nt)
          acc[mt][nt] =
              __builtin_amdgcn_mfma_f32_16x16x32_f16(af, bf[nt], acc[mt][nt], 0, 0, 0);
      }
    }
    // store K/V tiles to LDS. Wave wv covers cols [wv*64, wv*64+64):
    // hh = wv>>1, K if (wv&1)==0 else V; d = nt*16 + l15.
    {
      const int isv = wv & 1, hhw = wv >> 1;
      f16* dstb = isv ? V_s : K_s;
#pragma unroll
      for (int mt = 0; mt < 3; ++mt) {
#pragma unroll
        for (int nt = 0; nt < 4; ++nt) {
          int d = nt * 16 + l15;
#pragma unroll
          for (int r = 0; r < 4; ++r) {
            int mrow = mt * 16 + lhi * 4 + r;
            if (mrow < 34) {
              int bbw = mrow >= 17 ? 1 : 0;
              int m = mrow - 17 * bbw;
              dstb[((hhw * 2 + bbw) * 17 + m) * 64 + d] = (f16)acc[mt][nt][r];
            }
          }
        }
      }
    }
    __syncthreads();

    // ---- attention for heads hp*2, hp*2+1 ----
    for (int base = 0; base < 308; base += 256) {
      int item = base + tid;
      if (item < 308) {
        int hh = item / 154;
        int rem = item - 154 * hh;
        int bb = rem / 77;
        int n = rem - 77 * bb;
        int b = b0 + bb;
        const uint4* qr = (const uint4*)(q16h +
            (((size_t)(hp * 2 + hh) * 16 + (b & 15)) * 77 + n) * 64);
        uint4 qv[8];
#pragma unroll
        for (int i = 0; i < 8; ++i) qv[i] = qr[i];

        const f16* kb = K_s + ((hh * 2 + bb) * 17) * 64;
        float lg[17];
#pragma unroll
        for (int m = 0; m < 17; ++m) {
          const uint4* kr = (const uint4*)(kb + m * 64);
          float a0 = 0.f, a1 = 0.f, a2 = 0.f, a3 = 0.f;
#pragma unroll
          for (int c = 0; c < 8; ++c) {
            uint4 kk = kr[c];
            a0 = FDOT2(bch(kk.x), bch(qv[c].x), a0);
            a1 = FDOT2(bch(kk.y), bch(qv[c].y), a1);
            a2 = FDOT2(bch(kk.z), bch(qv[c].z), a2);
            a3 = FDOT2(bch(kk.w), bch(qv[c].w), a3);
          }
          lg[m] = (a0 + a1 + a2 + a3) * 0.125f;
        }
        float mx = lg[0];
#pragma unroll
        for (int m = 1; m < 17; ++m) mx = fmaxf(mx, lg[m]);
        float ssum = 0.f;
#pragma unroll
        for (int m = 0; m < 17; ++m) {
          float e = __expf(lg[m] - mx);
          lg[m] = e;
          ssum += e;
        }
        float inv = 1.0f / ssum;
        h2 w2[17];
#pragma unroll
        for (int m = 0; m < 17; ++m) w2[m] = pkrtz(lg[m], lg[m]);

        h2 ov[32];
        h2 zz;
        zz[0] = (f16)0.f;
        zz[1] = (f16)0.f;
#pragma unroll
        for (int c = 0; c < 32; ++c) ov[c] = zz;
        const f16* vb = V_s + ((hh * 2 + bb) * 17) * 64;
#pragma unroll
        for (int m = 0; m < 17; ++m) {
          const uint4* vr = (const uint4*)(vb + m * 64);
          h2 wm = w2[m];
#pragma unroll
          for (int c = 0; c < 8; ++c) {
            uint4 vv = vr[c];
            ov[c * 4 + 0] += wm * bch(vv.x);
            ov[c * 4 + 1] += wm * bch(vv.y);
            ov[c * 4 + 2] += wm * bch(vv.z);
            ov[c * 4 + 3] += wm * bch(vv.w);
          }
        }
        float* dst = out + ((size_t)b * 77 + n) * D + (hp * 2 + hh) * 64;
#pragma unroll
        for (int c = 0; c < 8; ++c) {
          h2 p0 = ov[c * 4 + 0], p1 = ov[c * 4 + 1];
          h2 p2 = ov[c * 4 + 2], p3 = ov[c * 4 + 3];
          f32x4 o0, o1;
          o0[0] = (float)p0[0] * inv;
          o0[1] = (float)p0[1] * inv;
          o0[2] = (float)p1[0] * inv;
          o0[3] = (float)p1[1] * inv;
          o1[0] = (float)p2[0] * inv;
          o1[1] = (float)p2[1] * inv;
          o1[2] = (float)p3[0] * inv;
          o1[3] = (float)p3[1] * inv;
          *(f32x4*)(dst + c * 8) = o0;
          *(f32x4*)(dst + c * 8 + 4) = o1;
        }
      }
    }
    __syncthreads();
  }
}

extern "C" void kernel_launch(void* const* d_in, const int* in_sizes, int n_in,
                              void* d_out, int out_size, void* d_ws, size_t ws_size,
                              hipStream_t stream) {
  const float* xf = (const float*)d_in[0];
  const float* x = (const float*)d_in[1];
  const float* tn_g = (const float*)d_in[2];
  const float* tn_b = (const float*)d_in[3];
  const float* n_g = (const float*)d_in[4];
  const float* n_b = (const float*)d_in[5];
  const float* Wq = (const float*)d_in[6];
  const float* bq = (const float*)d_in[7];
  const float* Wk = (const float*)d_in[8];
  const float* bk = (const float*)d_in[9];
  const float* Wv = (const float*)d_in[10];
  const float* bv = (const float*)d_in[11];
  float* out = (float*)d_out;

  char* ws = (char*)d_ws;
  f16* q16h = (f16*)ws;                         // 8*16*77*64*2 = 1,261,568 B
  f16* Wcat = (f16*)(ws + 1261568);             // 1024*512*2   = 1,048,576 B
  float* bcat = (float*)(ws + 2310144);         // 1024*4       = 4,096 B
  float* WqT = (float*)(ws + 2314240);          // 512*512*4    = 1,048,576 B

  prep_k<<<1536, 256, 0, stream>>>(Wq, Wk, bk, Wv, bv, Wcat, bcat, WqT);
  qproj_k<<<dim3(16, 7), 256, 0, stream>>>(xf, tn_g, tn_b, WqT, bq, q16h);
  fused_k<<<1944, 256, 0, stream>>>(x, n_g, n_b, Wcat, bcat, q16h, out);
}

// Round 4
// 531.898 us; speedup vs baseline: 1.5761x; 1.2023x over previous
//
#include <hip/hip_runtime.h>
#include <stdint.h>

#define D 512

typedef _Float16 f16;
typedef f16 f16x8 __attribute__((ext_vector_type(8)));
typedef f16 h2 __attribute__((ext_vector_type(2)));
typedef float f32x4 __attribute__((ext_vector_type(4)));

static __device__ __forceinline__ unsigned int bcu(h2 h) {
  return __builtin_bit_cast(unsigned int, h);
}
static __device__ __forceinline__ h2 pkrtz(float a, float b) {
  return __builtin_bit_cast(h2, __builtin_amdgcn_cvt_pkrtz(a, b));
}

// ---------------- prep: Wcat (f16, [h][k|v][d][i]) + bcat + WqT ----------------
__global__ __launch_bounds__(256) void prep_k(
    const float* __restrict__ Wq, const float* __restrict__ Wk,
    const float* __restrict__ bk, const float* __restrict__ Wv,
    const float* __restrict__ bv, f16* __restrict__ Wcat,
    float* __restrict__ bcat, float* __restrict__ WqT) {
  int bid = blockIdx.x, tid = threadIdx.x;
  if (bid < 1024) {
    int h = bid >> 7, kvs = (bid >> 6) & 1, d = bid & 63;
    int srow = h * 64 + d;
    const float* src = (kvs ? Wv : Wk) + (size_t)srow * D;
    f16* dst = Wcat + (size_t)bid * D;
    for (int i = tid; i < D; i += 256) dst[i] = (f16)src[i];
    if (tid == 0) bcat[bid] = (kvs ? bv : bk)[srow];
  } else {
    int i = bid - 1024;
    for (int o = tid; o < D; o += 256) WqT[(size_t)i * D + o] = Wq[(size_t)o * D + i];
  }
}

// ---------------- qproj: q16h[h][bs][n][64] (f16) = LN(xf) @ Wq^T + bq ----------------
__global__ __launch_bounds__(256) void qproj_k(
    const float* __restrict__ xf, const float* __restrict__ tn_g,
    const float* __restrict__ tn_b, const float* __restrict__ WqT,
    const float* __restrict__ bq, f16* __restrict__ q16h) {
  __shared__ __align__(16) float xnq[11][512];
  int bs = blockIdx.x, n0 = blockIdx.y * 11;
  int tid = threadIdx.x, wv = tid >> 6, lane = tid & 63;

  for (int lr = wv; lr < 11; lr += 4) {
    const f32x4* xr = (const f32x4*)(xf + ((size_t)(bs * 77 + n0 + lr)) * D);
    f32x4 va = xr[lane * 2], vb = xr[lane * 2 + 1];
    float s = va[0] + va[1] + va[2] + va[3] + vb[0] + vb[1] + vb[2] + vb[3];
    float sq = va[0] * va[0] + va[1] * va[1] + va[2] * va[2] + va[3] * va[3] +
               vb[0] * vb[0] + vb[1] * vb[1] + vb[2] * vb[2] + vb[3] * vb[3];
#pragma unroll
    for (int off = 32; off; off >>= 1) {
      s += __shfl_xor(s, off);
      sq += __shfl_xor(sq, off);
    }
    float mu = s * (1.0f / 512.0f);
    float var = sq * (1.0f / 512.0f) - mu * mu;
    float rstd = rsqrtf(var + 1e-5f);
    f32x4 ga = ((const f32x4*)tn_g)[lane * 2], gb = ((const f32x4*)tn_g)[lane * 2 + 1];
    f32x4 ba = ((const f32x4*)tn_b)[lane * 2], bb = ((const f32x4*)tn_b)[lane * 2 + 1];
    f32x4 r0, r1;
#pragma unroll
    for (int j = 0; j < 4; ++j) {
      r0[j] = (va[j] - mu) * rstd * ga[j] + ba[j];
      r1[j] = (vb[j] - mu) * rstd * gb[j] + bb[j];
    }
    *(f32x4*)&xnq[lr][lane * 8] = r0;
    *(f32x4*)&xnq[lr][lane * 8 + 4] = r1;
  }
  __syncthreads();

  int rows[3];
  int nr = 0;
  for (int lr = wv; lr < 11; lr += 4) rows[nr++] = lr;
  f32x4 acc[3][2];
  f32x4 bq0 = ((const f32x4*)bq)[lane], bq1 = ((const f32x4*)bq)[64 + lane];
#pragma unroll
  for (int r = 0; r < 3; ++r) {
    acc[r][0] = bq0;
    acc[r][1] = bq1;
  }
  for (int i = 0; i < 512; ++i) {
    const f32x4* wr = (const f32x4*)(WqT + (size_t)i * D);
    f32x4 w0 = wr[lane], w1 = wr[64 + lane];
#pragma unroll
    for (int r = 0; r < 3; ++r) {
      if (r < nr) {
        float xv = xnq[rows[r]][i];
        acc[r][0] += xv * w0;
        acc[r][1] += xv * w1;
      }
    }
  }
  int h0 = lane >> 4, d0 = (lane * 4) & 63;
  for (int r = 0; r < nr; ++r) {
    int n = n0 + rows[r];
    uint2 p0, p1;
    p0.x = bcu(pkrtz(acc[r][0][0], acc[r][0][1]));
    p0.y = bcu(pkrtz(acc[r][0][2], acc[r][0][3]));
    p1.x = bcu(pkrtz(acc[r][1][0], acc[r][1][1]));
    p1.y = bcu(pkrtz(acc[r][1][2], acc[r][1][3]));
    *(uint2*)(q16h + (((size_t)h0 * 16 + bs) * 77 + n) * 64 + d0) = p0;
    *(uint2*)(q16h + (((size_t)(h0 + 4) * 16 + bs) * 77 + n) * 64 + d0) = p1;
  }
}

// ---------------- fused: LN(x) -> k,v proj (MFMA) -> MFMA attention -> out ----------------
// block: 2 batches (34 rows), 256 threads (4 waves), loop over 4 head-pairs.
// LDS (single raw block, byte offsets):
//   xn : [34 rows][1024B]     byte = r*1024 + (col16B ^ ((r&7)<<4))        (2-way, free)
//   K_s: [4*17 rows][144B]    row = combo*17 + m, col d*2                  (2-way reads)
//   V_t: [4*64 rows][64B]     row = combo*64 + d, byte = m*2 ^ ((d&3)<<4)  (4-way, rare)
//   P  : per-wave [16][64B]   row = n, byte = m*2 ^ ((n&3)<<4)
// combo = hh*2 + bb. m-pad (17..31) of V_t/P zero-initialized once; S cols >16 masked.
#define XN_OFF 0
#define KS_OFF 34816
#define VT_OFF 44608
#define P_OFF 60992
#define LDS_TOTAL 65088

__global__ __launch_bounds__(256, 2) void fused_k(
    const float* __restrict__ x, const float* __restrict__ n_g,
    const float* __restrict__ n_b, const f16* __restrict__ Wcat,
    const float* __restrict__ bcat, const f16* __restrict__ q16h,
    float* __restrict__ out) {
  __shared__ __align__(16) unsigned char lds[LDS_TOTAL];
  const int b0 = blockIdx.x * 2;
  const int tid = threadIdx.x, wv = tid >> 6, lane = tid & 63;
  const int l15 = lane & 15, lhi = lane >> 4;

  // Zero V_t + P pad regions (contiguous 20480B)
  {
    uint4 z;
    z.x = z.y = z.z = z.w = 0u;
#pragma unroll
    for (int k = 0; k < 5; ++k)
      *reinterpret_cast<uint4*>(lds + VT_OFF + tid * 16 + k * 4096) = z;
  }

  // Phase 1: LayerNorm -> xn f16 (swizzled)
  for (int rr = wv; rr < 34; rr += 4) {
    const f32x4* xr = (const f32x4*)(x + ((size_t)(b0 * 17 + rr)) * D);
    f32x4 va = xr[lane * 2], vb = xr[lane * 2 + 1];
    float s = va[0] + va[1] + va[2] + va[3] + vb[0] + vb[1] + vb[2] + vb[3];
    float sq = va[0] * va[0] + va[1] * va[1] + va[2] * va[2] + va[3] * va[3] +
               vb[0] * vb[0] + vb[1] * vb[1] + vb[2] * vb[2] + vb[3] * vb[3];
#pragma unroll
    for (int off = 32; off; off >>= 1) {
      s += __shfl_xor(s, off);
      sq += __shfl_xor(sq, off);
    }
    float mu = s * (1.0f / 512.0f);
    float var = sq * (1.0f / 512.0f) - mu * mu;
    float rstd = rsqrtf(var + 1e-5f);
    f32x4 ga = ((const f32x4*)n_g)[lane * 2], gb = ((const f32x4*)n_g)[lane * 2 + 1];
    f32x4 ba = ((const f32x4*)n_b)[lane * 2], bb = ((const f32x4*)n_b)[lane * 2 + 1];
    float f0 = (va[0] - mu) * rstd * ga[0] + ba[0];
    float f1 = (va[1] - mu) * rstd * ga[1] + ba[1];
    float f2 = (va[2] - mu) * rstd * ga[2] + ba[2];
    float f3 = (va[3] - mu) * rstd * ga[3] + ba[3];
    float f4 = (vb[0] - mu) * rstd * gb[0] + bb[0];
    float f5 = (vb[1] - mu) * rstd * gb[1] + bb[1];
    float f6 = (vb[2] - mu) * rstd * gb[2] + bb[2];
    float f7 = (vb[3] - mu) * rstd * gb[3] + bb[3];
    uint4 u;
    u.x = bcu(pkrtz(f0, f1));
    u.y = bcu(pkrtz(f2, f3));
    u.z = bcu(pkrtz(f4, f5));
    u.w = bcu(pkrtz(f6, f7));
    *reinterpret_cast<uint4*>(lds + XN_OFF + rr * 1024 + ((lane * 16) ^ ((rr & 7) << 4))) = u;
  }
  __syncthreads();

  const int hh = wv >> 1, bb = wv & 1;     // attention combo = wv
  const int b = b0 + bb, bs = b & 15;
  const int isv = wv & 1, hhw = wv >> 1;   // projection role

  for (int hp = 0; hp < 4; ++hp) {
    const int head = hp * 2 + hh;
    // ---- Q fragments for this wave's (head, bs): n rows = nt*16+l15, k = d ----
    f16x8 qf[5][2];
    const f16* qbase = q16h + (((size_t)head * 16 + bs) * 77) * 64;
#pragma unroll
    for (int nt = 0; nt < 5; ++nt)
#pragma unroll
      for (int ks2 = 0; ks2 < 2; ++ks2)
        qf[nt][ks2] = *(const f16x8*)(qbase + (nt * 16 + l15) * 64 + ks2 * 32 + lhi * 8);

    // ---- k,v projection via MFMA: cols = Wcat rows [hp*256, hp*256+256) ----
    const int ntb = wv * 4;
    f32x4 acc[3][4];
#pragma unroll
    for (int nt = 0; nt < 4; ++nt) {
      float bias = bcat[hp * 256 + (ntb + nt) * 16 + l15];
      f32x4 bi = {bias, bias, bias, bias};
#pragma unroll
      for (int mt = 0; mt < 3; ++mt) acc[mt][nt] = bi;
    }
    const f16* wbase = Wcat + (size_t)(hp * 256 + ntb * 16 + l15) * D;
    for (int ks = 0; ks < 16; ++ks) {
      f16x8 bf[4];
#pragma unroll
      for (int nt = 0; nt < 4; ++nt)
        bf[nt] = *(const f16x8*)(wbase + (size_t)nt * 16 * D + ks * 32 + lhi * 8);
#pragma unroll
      for (int mt = 0; mt < 3; ++mt) {
        int arow = mt * 16 + l15;
        f16x8 af = *(const f16x8*)(lds + XN_OFF + arow * 1024 +
                                   ((ks * 64 + lhi * 16) ^ ((arow & 7) << 4)));
#pragma unroll
        for (int nt = 0; nt < 4; ++nt)
          acc[mt][nt] =
              __builtin_amdgcn_mfma_f32_16x16x32_f16(af, bf[nt], acc[mt][nt], 0, 0, 0);
      }
    }
    // store K -> K_s [combo*17+m][d*2]; V -> V_t [combo*64+d][m*2 ^ ((d&3)<<4)]
#pragma unroll
    for (int mt = 0; mt < 3; ++mt) {
#pragma unroll
      for (int nt = 0; nt < 4; ++nt) {
        int d = nt * 16 + l15;
#pragma unroll
        for (int r = 0; r < 4; ++r) {
          int mrow = mt * 16 + lhi * 4 + r;
          if (mrow < 34) {
            int bbw = mrow >= 17 ? 1 : 0;
            int m = mrow - 17 * bbw;
            int combo = hhw * 2 + bbw;
            f16 val = (f16)acc[mt][nt][r];
            if (isv)
              *(f16*)(lds + VT_OFF + (combo * 64 + d) * 64 + ((m * 2) ^ ((d & 3) << 4))) = val;
            else
              *(f16*)(lds + KS_OFF + (combo * 17 + m) * 144 + d * 2) = val;
          }
        }
      }
    }
    __syncthreads();

    // ---- MFMA attention: this wave handles (head, b) = combo wv ----
    f16x8 kf[2][2], vf[4];
#pragma unroll
    for (int mt = 0; mt < 2; ++mt)
#pragma unroll
      for (int ks2 = 0; ks2 < 2; ++ks2)
        kf[mt][ks2] = *(const f16x8*)(lds + KS_OFF + (wv * 17 + mt * 16 + l15) * 144 +
                                      ks2 * 64 + lhi * 16);
#pragma unroll
    for (int dt = 0; dt < 4; ++dt)
      vf[dt] = *(const f16x8*)(lds + VT_OFF + (wv * 64 + dt * 16 + l15) * 64 +
                               ((lhi * 16) ^ ((l15 & 3) << 4)));

    unsigned char* Pw = lds + P_OFF + wv * 1024;
    float* obase = out + ((size_t)b * 77) * 512 + head * 64;
    const float C2 = 0.18033688011112042f;  // log2(e)/8

#pragma unroll
    for (int nt = 0; nt < 5; ++nt) {
      f32x4 z = {0.f, 0.f, 0.f, 0.f};
      f32x4 s0 = z, s1 = z;
      s0 = __builtin_amdgcn_mfma_f32_16x16x32_f16(qf[nt][0], kf[0][0], s0, 0, 0, 0);
      s0 = __builtin_amdgcn_mfma_f32_16x16x32_f16(qf[nt][1], kf[0][1], s0, 0, 0, 0);
      s1 = __builtin_amdgcn_mfma_f32_16x16x32_f16(qf[nt][0], kf[1][0], s1, 0, 0, 0);
      s1 = __builtin_amdgcn_mfma_f32_16x16x32_f16(qf[nt][1], kf[1][1], s1, 0, 0, 0);
      if (l15 != 0) {
        s1[0] = -1e30f; s1[1] = -1e30f; s1[2] = -1e30f; s1[3] = -1e30f;
      }
      f32x4 m4;
#pragma unroll
      for (int r = 0; r < 4; ++r) m4[r] = fmaxf(s0[r], s1[r]);
#pragma unroll
      for (int off = 1; off < 16; off <<= 1) {
#pragma unroll
        for (int r = 0; r < 4; ++r) m4[r] = fmaxf(m4[r], __shfl_xor(m4[r], off));
      }
      f32x4 e0, e1, sum;
#pragma unroll
      for (int r = 0; r < 4; ++r) {
        e0[r] = exp2f((s0[r] - m4[r]) * C2);
        e1[r] = exp2f((s1[r] - m4[r]) * C2);
        sum[r] = e0[r] + e1[r];
      }
#pragma unroll
      for (int off = 1; off < 16; off <<= 1) {
#pragma unroll
        for (int r = 0; r < 4; ++r) sum[r] += __shfl_xor(sum[r], off);
      }
#pragma unroll
      for (int r = 0; r < 4; ++r) {
        float inv = 1.0f / sum[r];
        int prow = lhi * 4 + r;
        *(f16*)(Pw + prow * 64 + ((l15 * 2) ^ ((prow & 3) << 4))) = (f16)(e0[r] * inv);
        if (l15 == 0)
          *(f16*)(Pw + prow * 64 + (32 ^ ((prow & 3) << 4))) = (f16)(e1[r] * inv);
      }
      f16x8 pa = *(const f16x8*)(Pw + l15 * 64 + ((lhi * 16) ^ ((l15 & 3) << 4)));
#pragma unroll
      for (int dt = 0; dt < 4; ++dt) {
        f32x4 o = {0.f, 0.f, 0.f, 0.f};
        o = __builtin_amdgcn_mfma_f32_16x16x32_f16(pa, vf[dt], o, 0, 0, 0);
#pragma unroll
        for (int r = 0; r < 4; ++r) {
          int n = nt * 16 + lhi * 4 + r;
          if (n < 77) obase[(size_t)n * 512 + dt * 16 + l15] = o[r];
        }
      }
    }
    __syncthreads();
  }
}

extern "C" void kernel_launch(void* const* d_in, const int* in_sizes, int n_in,
                              void* d_out, int out_size, void* d_ws, size_t ws_size,
                              hipStream_t stream) {
  const float* xf = (const float*)d_in[0];
  const float* x = (const float*)d_in[1];
  const float* tn_g = (const float*)d_in[2];
  const float* tn_b = (const float*)d_in[3];
  const float* n_g = (const float*)d_in[4];
  const float* n_b = (const float*)d_in[5];
  const float* Wq = (const float*)d_in[6];
  const float* bq = (const float*)d_in[7];
  const float* Wk = (const float*)d_in[8];
  const float* bk = (const float*)d_in[9];
  const float* Wv = (const float*)d_in[10];
  const float* bv = (const float*)d_in[11];
  float* out = (float*)d_out;

  char* ws = (char*)d_ws;
  f16* q16h = (f16*)ws;                     // 8*16*77*64*2 = 1,261,568 B
  f16* Wcat = (f16*)(ws + 1261568);         // 1024*512*2   = 1,048,576 B
  float* bcat = (float*)(ws + 2310144);     // 1024*4       = 4,096 B
  float* WqT = (float*)(ws + 2314240);      // 512*512*4    = 1,048,576 B

  prep_k<<<1536, 256, 0, stream>>>(Wq, Wk, bk, Wv, bv, Wcat, bcat, WqT);
  qproj_k<<<dim3(16, 7), 256, 0, stream>>>(xf, tn_g, tn_b, WqT, bq, q16h);
  fused_k<<<1944, 256, 0, stream>>>(x, n_g, n_b, Wcat, bcat, q16h, out);
}